// Round 11
// baseline (672.701 us; speedup 1.0000x reference)
//
#include <hip/hip_runtime.h>
#include <stdint.h>
#include <math.h>

#define IN_DIM 512
#define HID    256
#define OUTD   128
#define LN_EPS 1e-5f
#define NSLOT  2048

typedef unsigned short u16;
typedef unsigned int   u32;
typedef unsigned char  u8;
typedef short short8 __attribute__((ext_vector_type(8)));
typedef float f32x4  __attribute__((ext_vector_type(4)));

__device__ __forceinline__ float bf2f(u32 h) {
  union { u32 u; float f; } c; c.u = h << 16; return c.f;
}
__device__ __forceinline__ u16 f2bf(float f) {
  union { float f; u32 u; } c; c.f = f;
  u32 u = c.u;
  return (u16)((u + 0x7FFFu + ((u >> 16) & 1u)) >> 16);  // RNE
}
// sign-extended int8 lane w of a u32, as float
template <int W>
__device__ __forceinline__ float i8f(u32 word) {
  return (float)((int)(word << (24 - 8 * W)) >> 24);
}

__device__ __forceinline__ void gload_lds16(const void* g, void* l) {
  __builtin_amdgcn_global_load_lds((const __attribute__((address_space(1))) void*)g,
                                   (__attribute__((address_space(3))) void*)l, 16, 0, 0);
}

// ================= K1: mega-prep (block-region dispatch) =====================
__global__ __launch_bounds__(256) void k_prep(
    const float* __restrict__ x, u16* __restrict__ x_bf, int n4,
    const int* __restrict__ edst, int* __restrict__ deg, int E,
    const float* __restrict__ bq1, const float* __restrict__ bk1,
    const float* __restrict__ bv1, const float* __restrict__ bs1,
    const float* __restrict__ bq2, const float* __restrict__ bk2,
    const float* __restrict__ bv2, const float* __restrict__ bs2,
    float* __restrict__ bc1, float* __restrict__ bc2,
    const float* __restrict__ Wq1, const float* __restrict__ Wk1,
    const float* __restrict__ Wv1, const float* __restrict__ Ws1,
    const float* __restrict__ Wq2, const float* __restrict__ Wk2,
    const float* __restrict__ Wv2, const float* __restrict__ Ws2,
    u16* __restrict__ Wt1, u16* __restrict__ Wt2,
    int b_cvt, int b_hist) {
  __shared__ u16 t[32][33];
  int blk = blockIdx.x;
  int tid = threadIdx.x;
  if (blk < b_cvt) {
    int id = blk * 256 + tid;
    if (id < n4) {
      const float4 v = ((const float4*)x)[id];
      ushort4 o;
      o.x = f2bf(v.x); o.y = f2bf(v.y); o.z = f2bf(v.z); o.w = f2bf(v.w);
      ((ushort4*)x_bf)[id] = o;
    }
    return;
  }
  blk -= b_cvt;
  if (blk < b_hist) {
    int e = blk * 256 + tid;
    if (e < E) atomicAdd(&deg[edst[e]], 1);
    return;
  }
  blk -= b_hist;
  if (blk < 6) {
    int id = blk * 256 + tid;
    if (id < 4 * HID) {
      const float* s = (id < HID) ? bq1 : (id < 2 * HID) ? bk1 : (id < 3 * HID) ? bv1 : bs1;
      bc1[id] = s[id & (HID - 1)];
    } else if (id < 4 * HID + 4 * OUTD) {
      int j = id - 4 * HID;
      const float* s = (j < OUTD) ? bq2 : (j < 2 * OUTD) ? bk2 : (j < 3 * OUTD) ? bv2 : bs2;
      bc2[j] = s[j & (OUTD - 1)];
    }
    return;
  }
  blk -= 6;
  int tx = tid & 31, ty = tid >> 5;
  if (blk < 512) {  // W1: K=512, Nw=256; per-mat 16x8 tiles
    int mat = blk >> 7, r = blk & 127;
    int k0 = (r >> 3) * 32, n0 = (r & 7) * 32;
    const float* src = (mat == 0) ? Wq1 : (mat == 1) ? Wk1 : (mat == 2) ? Wv1 : Ws1;
    u16* dst = Wt1 + (size_t)mat * IN_DIM * HID;
#pragma unroll
    for (int i = 0; i < 32; i += 8)
      t[ty + i][tx] = f2bf(src[(size_t)(k0 + ty + i) * HID + n0 + tx]);
    __syncthreads();
#pragma unroll
    for (int i = 0; i < 32; i += 8)
      dst[(size_t)(n0 + ty + i) * IN_DIM + k0 + tx] = t[tx][ty + i];
    return;
  }
  blk -= 512;
  {  // W2: K=256, Nw=128; per-mat 8x4 tiles
    int mat = blk >> 5, r = blk & 31;
    int k0 = (r >> 2) * 32, n0 = (r & 3) * 32;
    const float* src = (mat == 0) ? Wq2 : (mat == 1) ? Wk2 : (mat == 2) ? Wv2 : Ws2;
    u16* dst = Wt2 + (size_t)mat * HID * OUTD;
#pragma unroll
    for (int i = 0; i < 32; i += 8)
      t[ty + i][tx] = f2bf(src[(size_t)(k0 + ty + i) * OUTD + n0 + tx]);
    __syncthreads();
#pragma unroll
    for (int i = 0; i < 32; i += 8)
      dst[(size_t)(n0 + ty + i) * HID + k0 + tx] = t[tx][ty + i];
  }
}

// ================= K2a/b/c: parallel 3-kernel scan ===========================
__global__ void k_block_sum(const int* __restrict__ deg, int* __restrict__ bsum, int n) {
  __shared__ int sm[256];
  int i = blockIdx.x * 256 + threadIdx.x;
  sm[threadIdx.x] = (i < n) ? deg[i] : 0;
  __syncthreads();
  for (int off = 128; off > 0; off >>= 1) {
    if (threadIdx.x < off) sm[threadIdx.x] += sm[threadIdx.x + off];
    __syncthreads();
  }
  if (threadIdx.x == 0) bsum[blockIdx.x] = sm[0];
}

__global__ void k_scan_bsum(const int* __restrict__ bsum, int* __restrict__ boff, int nb) {
  __shared__ int sm[256];
  int t = threadIdx.x;
  int v = (t < nb) ? bsum[t] : 0;
  sm[t] = v;
  __syncthreads();
  for (int off = 1; off < 256; off <<= 1) {
    int tmp = (t >= off) ? sm[t - off] : 0;
    __syncthreads();
    sm[t] += tmp;
    __syncthreads();
  }
  if (t < nb) boff[t] = sm[t] - v;  // exclusive
}

__global__ void k_scan_final(const int* __restrict__ deg, const int* __restrict__ boff,
                             int* __restrict__ offsets, int* __restrict__ cur,
                             int n, int total) {
  __shared__ int sm[256];
  int t = threadIdx.x;
  int i = blockIdx.x * 256 + t;
  int v = (i < n) ? deg[i] : 0;
  sm[t] = v;
  __syncthreads();
  for (int off = 1; off < 256; off <<= 1) {
    int tmp = (t >= off) ? sm[t - off] : 0;
    __syncthreads();
    sm[t] += tmp;
    __syncthreads();
  }
  if (i < n) {
    int o = boff[blockIdx.x] + sm[t] - v;
    offsets[i] = o;
    cur[i] = o;
  }
  if (i == 0) offsets[n] = total;
}

// ================= K3/K7: bf16 NT GEMM 128x256, split Cb/Ck epilogue =========
// Columns [cklo,ckhi) -> bf16 scratch Ck[row*sK + c-cklo] (to be quantized);
// others -> Cb[row*sB + c - (c>=ckhi ? ckhi-cklo : 0)]. Optional scatter tail.
__global__ __launch_bounds__(256, 2) void k_gemm(
    const u16* __restrict__ A, const u16* __restrict__ Bt, const float* __restrict__ bias,
    u16* __restrict__ Cb, u16* __restrict__ Ck,
    int M, int K, int Nt, int mbx, int cklo, int ckhi, int sB, int sK,
    int gemm_blocks,
    const int* __restrict__ esrc, const int* __restrict__ edst,
    int* __restrict__ cur, int* __restrict__ ssrc, int E) {
  if ((int)blockIdx.x >= gemm_blocks) {  // scatter region
    int e = (blockIdx.x - gemm_blocks) * 256 + threadIdx.x;
    if (e < E) {
      int d = edst[e];
      int pos = atomicAdd(&cur[d], 1);
      ssrc[pos] = esrc[e];
    }
    return;
  }
  __shared__ __align__(16) u16 As[128 * 32];   // 8 KB
  __shared__ __align__(16) u16 Bs[256 * 32];   // 16 KB
  const int tid = threadIdx.x;
  const int bm0 = (blockIdx.x % mbx) * 128;
  const int bn0 = (blockIdx.x / mbx) * 256;
  const int wave = tid >> 6, lane = tid & 63;
  const int q = lane >> 4, r16 = lane & 15;
  const int wm = (wave >> 1) * 64;
  const int wn = (wave & 1) * 128;

  f32x4 acc[4][8];
#pragma unroll
  for (int i = 0; i < 4; i++)
#pragma unroll
    for (int j = 0; j < 8; j++) acc[i][j] = (f32x4){0.f, 0.f, 0.f, 0.f};

  for (int kt = 0; kt < K; kt += 32) {
#pragma unroll
    for (int j = 0; j < 2; ++j) {
      int t = j * 256 + tid;
      gload_lds16(A + (size_t)(bm0 + (t >> 2)) * K + kt + (t & 3) * 8, &As[t * 8]);
    }
#pragma unroll
    for (int j = 0; j < 4; ++j) {
      int t = j * 256 + tid;
      gload_lds16(Bt + (size_t)(bn0 + (t >> 2)) * K + kt + (t & 3) * 8, &Bs[t * 8]);
    }
    __syncthreads();
    short8 bfr[8];
#pragma unroll
    for (int j = 0; j < 8; ++j)
      bfr[j] = *(const short8*)(&Bs[(wn + j * 16 + r16) * 32 + q * 8]);
#pragma unroll
    for (int i = 0; i < 4; ++i) {
      short8 af = *(const short8*)(&As[(wm + i * 16 + r16) * 32 + q * 8]);
#pragma unroll
      for (int j = 0; j < 8; ++j)
        acc[i][j] = __builtin_amdgcn_mfma_f32_16x16x32_bf16(af, bfr[j], acc[i][j], 0, 0, 0);
    }
    __syncthreads();
  }

  const int wk = ckhi - cklo;
#pragma unroll
  for (int i = 0; i < 4; i++) {
#pragma unroll
    for (int r = 0; r < 4; r++) {
      int grow = bm0 + wm + i * 16 + q * 4 + r;   // C/D: row = quad*4 + reg
      if (grow >= M) continue;
#pragma unroll
      for (int j = 0; j < 8; j++) {
        int gcol = bn0 + wn + j * 16 + r16;       // C/D: col = lane&15
        float v = acc[i][j][r] + bias[gcol];
        if (gcol < cklo) Cb[(size_t)grow * sB + gcol] = f2bf(v);
        else if (gcol < ckhi) Ck[(size_t)grow * sK + gcol - cklo] = f2bf(v);
        else Cb[(size_t)grow * sB + gcol - wk] = f2bf(v);
      }
    }
  }
}

// ================= K4/K8: int8 quantization (per-section row-max scale) ======
// one wave per (node,section): SECW bf16 -> SECW int8 + 1 f32 scale
template <int SECW, int NSEC>
__global__ __launch_bounds__(256) void k_quant(
    const u16* __restrict__ src, u8* __restrict__ dst,
    float* __restrict__ sc, int n) {
  constexpr int VPL = SECW / 64;  // 4 or 2
  int gw = (blockIdx.x * blockDim.x + threadIdx.x) >> 6;
  int lane = threadIdx.x & 63;
  int node = gw / NSEC, sec = gw - node * NSEC;
  if (node >= n) return;
  const u16* p = src + (size_t)node * (NSEC * SECW) + sec * SECW + lane * VPL;
  float f[VPL];
  if constexpr (VPL == 4) {
    uint2 r = *(const uint2*)p;
    f[0] = bf2f(r.x & 0xffffu); f[1] = bf2f(r.x >> 16);
    f[2] = bf2f(r.y & 0xffffu); f[3] = bf2f(r.y >> 16);
  } else {
    u32 r = *(const u32*)p;
    f[0] = bf2f(r & 0xffffu); f[1] = bf2f(r >> 16);
  }
  float amax = 0.f;
#pragma unroll
  for (int w = 0; w < VPL; w++) amax = fmaxf(amax, fabsf(f[w]));
#pragma unroll
  for (int off = 32; off > 0; off >>= 1) amax = fmaxf(amax, __shfl_xor(amax, off, 64));
  float rs = (amax > 0.f) ? 127.0f / amax : 0.f;
  u32 packed = 0;
#pragma unroll
  for (int w = 0; w < VPL; w++) {
    int qv = (int)rintf(f[w] * rs);
    packed |= ((u32)(qv & 0xff)) << (8 * w);
  }
  u8* d = dst + (size_t)node * (NSEC * SECW) + sec * SECW + lane * VPL;
  if constexpr (VPL == 4) *(u32*)d = packed;
  else *(u16*)d = (u16)packed;
  if (lane == 0) sc[node * NSEC + sec] = amax / 127.0f;
}

// ================= K5/K9: conv — int8 K (and V in L1), online softmax ========
// V_I8=true (L1): qs=[Q|S] stride 2H; k8=[K|V] int8 stride 2H bytes; sc[node*2]
// V_I8=false(L2): qs=[Q|V|S] stride 3H; k8=[K] int8 stride H bytes; sc[node]
template <int H, bool OUT_BF16, bool V_I8>
__global__ __launch_bounds__(256) void k_conv(
    const u16* __restrict__ qs, const u8* __restrict__ k8,
    const float* __restrict__ sc,
    const int* __restrict__ offsets, const int* __restrict__ ssrc,
    u16* __restrict__ out_bf, float* __restrict__ out_f, int n, float scale,
    float* __restrict__ ssum, float* __restrict__ ssq) {
  constexpr int VPL = H / 64;                    // 4 or 2
  constexpr int QSTR = V_I8 ? 2 * H : 3 * H;
  constexpr int SOFF = V_I8 ? H : 2 * H;
  constexpr int KSTR = V_I8 ? 2 * H : H;         // bytes
  int gw = (blockIdx.x * blockDim.x + threadIdx.x) >> 6;
  int wave = threadIdx.x >> 6;
  int lane = threadIdx.x & 63;
  if (gw >= n) return;
  const u16* base = qs + (size_t)gw * QSTR;
  float qf[VPL];
  if constexpr (VPL == 4) {
    uint2 rq = *(const uint2*)(base + lane * 4);
    qf[0] = bf2f(rq.x & 0xffffu); qf[1] = bf2f(rq.x >> 16);
    qf[2] = bf2f(rq.y & 0xffffu); qf[3] = bf2f(rq.y >> 16);
  } else {
    u32 rq = *(const u32*)(base + lane * 2);
    qf[0] = bf2f(rq & 0xffffu); qf[1] = bf2f(rq >> 16);
  }
  int beg = offsets[gw], end = offsets[gw + 1];
  float m = -INFINITY, l = 0.f;
  float agg[VPL];
#pragma unroll
  for (int w = 0; w < VPL; w++) agg[w] = 0.f;

  auto kload = [&](int s) -> u32 {
    const u8* kp = k8 + (size_t)s * KSTR;
    if constexpr (VPL == 4) return *(const u32*)(kp + lane * 4);
    else return (u32)*(const u16*)(kp + lane * 2);
  };
  auto vload = [&](int s) -> u32 {  // V: int8 u32 (L1) or bf16-pair u32 low (L2 VPL=2)
    if constexpr (V_I8) return *(const u32*)(k8 + (size_t)s * KSTR + H + lane * 4);
    else return *(const u32*)(qs + (size_t)s * QSTR + H + lane * 2);
  };
  auto vload2 = [&](int s) -> u32 {  // second half of bf16 V for VPL==4 (unused: L1 is int8)
    return 0u;
  };
  (void)vload2;
  auto dotk = [&](u32 kq) -> float {
    float d = 0.f;
    d += qf[0] * i8f<0>(kq);
    d += qf[1] * i8f<1>(kq);
    if constexpr (VPL == 4) {
      d += qf[2] * i8f<2>(kq);
      d += qf[3] * i8f<3>(kq);
    }
    return d;
  };

  int i = beg;
  for (; i + 4 <= end; i += 4) {
    int s0 = ssrc[i], s1 = ssrc[i + 1], s2 = ssrc[i + 2], s3 = ssrc[i + 3];
    u32 kq0 = kload(s0), kq1 = kload(s1), kq2 = kload(s2), kq3 = kload(s3);
    u32 v0 = vload(s0), v1 = vload(s1), v2 = vload(s2), v3 = vload(s3);
    float ks0, ks1, ks2, ks3, vs0, vs1, vs2, vs3;
    if constexpr (V_I8) {
      float2 a0 = *(const float2*)(sc + s0 * 2), a1 = *(const float2*)(sc + s1 * 2);
      float2 a2 = *(const float2*)(sc + s2 * 2), a3 = *(const float2*)(sc + s3 * 2);
      ks0 = a0.x; vs0 = a0.y; ks1 = a1.x; vs1 = a1.y;
      ks2 = a2.x; vs2 = a2.y; ks3 = a3.x; vs3 = a3.y;
    } else {
      ks0 = sc[s0]; ks1 = sc[s1]; ks2 = sc[s2]; ks3 = sc[s3];
      vs0 = vs1 = vs2 = vs3 = 1.f;
    }
    float d0 = dotk(kq0), d1 = dotk(kq1), d2 = dotk(kq2), d3 = dotk(kq3);
#pragma unroll
    for (int off = 32; off > 0; off >>= 1) {
      d0 += __shfl_xor(d0, off, 64);
      d1 += __shfl_xor(d1, off, 64);
      d2 += __shfl_xor(d2, off, 64);
      d3 += __shfl_xor(d3, off, 64);
    }
    d0 *= scale * ks0; d1 *= scale * ks1; d2 *= scale * ks2; d3 *= scale * ks3;
    float cm = fmaxf(fmaxf(d0, d1), fmaxf(d2, d3));
    float nm = fmaxf(m, cm);
    float sfac = __expf(m - nm);  // m=-inf first round -> 0
    float p0 = __expf(d0 - nm), p1 = __expf(d1 - nm);
    float p2 = __expf(d2 - nm), p3 = __expf(d3 - nm);
    m = nm;
    l = l * sfac + (p0 + p1) + (p2 + p3);
    if constexpr (V_I8) { p0 *= vs0; p1 *= vs1; p2 *= vs2; p3 *= vs3; }
#pragma unroll
    for (int w = 0; w < VPL; w++) {
      float f0, f1, f2v, f3;
      if constexpr (V_I8) {
        f0 = (w == 0) ? i8f<0>(v0) : (w == 1) ? i8f<1>(v0) : (w == 2) ? i8f<2>(v0) : i8f<3>(v0);
        f1 = (w == 0) ? i8f<0>(v1) : (w == 1) ? i8f<1>(v1) : (w == 2) ? i8f<2>(v1) : i8f<3>(v1);
        f2v = (w == 0) ? i8f<0>(v2) : (w == 1) ? i8f<1>(v2) : (w == 2) ? i8f<2>(v2) : i8f<3>(v2);
        f3 = (w == 0) ? i8f<0>(v3) : (w == 1) ? i8f<1>(v3) : (w == 2) ? i8f<2>(v3) : i8f<3>(v3);
      } else {
        u32 sh = 16 * (w & 1);
        f0 = bf2f((v0 >> sh) & 0xffffu);
        f1 = bf2f((v1 >> sh) & 0xffffu);
        f2v = bf2f((v2 >> sh) & 0xffffu);
        f3 = bf2f((v3 >> sh) & 0xffffu);
      }
      agg[w] = agg[w] * sfac + p0 * f0 + p1 * f1 + p2 * f2v + p3 * f3;
    }
  }
  for (; i < end; ++i) {
    int s = ssrc[i];
    u32 kq = kload(s);
    u32 vr = vload(s);
    float ks, vs;
    if constexpr (V_I8) {
      float2 a = *(const float2*)(sc + s * 2);
      ks = a.x; vs = a.y;
    } else { ks = sc[s]; vs = 1.f; }
    float d = dotk(kq);
#pragma unroll
    for (int off = 32; off > 0; off >>= 1) d += __shfl_xor(d, off, 64);
    float score = d * scale * ks;
    float nm = fmaxf(m, score);
    float sfac = __expf(m - nm);
    float p = __expf(score - nm);
    m = nm;
    l = l * sfac + p;
    float pv = V_I8 ? p * vs : p;
#pragma unroll
    for (int w = 0; w < VPL; w++) {
      float vf;
      if constexpr (V_I8)
        vf = (w == 0) ? i8f<0>(vr) : (w == 1) ? i8f<1>(vr) : (w == 2) ? i8f<2>(vr) : i8f<3>(vr);
      else vf = bf2f((vr >> (16 * (w & 1))) & 0xffffu);
      agg[w] = agg[w] * sfac + pv * vf;
    }
  }

  float sf[VPL];
  {
    const u16* sp = base + SOFF;
    if constexpr (VPL == 4) {
      uint2 rs = *(const uint2*)(sp + lane * 4);
      sf[0] = bf2f(rs.x & 0xffffu); sf[1] = bf2f(rs.x >> 16);
      sf[2] = bf2f(rs.y & 0xffffu); sf[3] = bf2f(rs.y >> 16);
    } else {
      u32 rs = *(const u32*)(sp + lane * 2);
      sf[0] = bf2f(rs & 0xffffu); sf[1] = bf2f(rs >> 16);
    }
  }
  float inv = (end > beg) ? 1.f / l : 0.f;
  float r[VPL];
#pragma unroll
  for (int w = 0; w < VPL; w++) {
    r[w] = agg[w] * inv + sf[w];
    if (OUT_BF16) out_bf[(size_t)gw * H + lane * VPL + w] = f2bf(r[w]);
    else out_f[(size_t)gw * H + lane * VPL + w] = r[w];
  }

  // spread-slot stats: no barrier, no LDS, 4096 distinct addresses
  float s = 0.f, s2 = 0.f;
#pragma unroll
  for (int w = 0; w < VPL; w++) { s += r[w]; s2 += r[w] * r[w]; }
#pragma unroll
  for (int off = 32; off > 0; off >>= 1) {
    s += __shfl_xor(s, off, 64);
    s2 += __shfl_xor(s2, off, 64);
  }
  if (lane == 0) {
    int slot = (blockIdx.x * 4 + wave) & (NSLOT - 1);
    atomicAdd(&ssum[slot], s);
    atomicAdd(&ssq[slot], s2);
  }
}

// ================= K6/K10: layernorm apply (inline slot reduce) ==============
__device__ __forceinline__ void slot_stats(const float* __restrict__ ssum,
                                           const float* __restrict__ ssq,
                                           double cnt, float& mu, float& inv) {
  __shared__ double rs[256], rq[256];
  double ls = 0.0, lq = 0.0;
  for (int i = threadIdx.x; i < NSLOT; i += 256) {
    ls += (double)ssum[i];
    lq += (double)ssq[i];
  }
  rs[threadIdx.x] = ls; rq[threadIdx.x] = lq;
  __syncthreads();
  for (int off = 128; off > 0; off >>= 1) {
    if (threadIdx.x < off) { rs[threadIdx.x] += rs[threadIdx.x + off]; rq[threadIdx.x] += rq[threadIdx.x + off]; }
    __syncthreads();
  }
  double mud = rs[0] / cnt;
  double var = rq[0] / cnt - mud * mud;
  if (var < 0.0) var = 0.0;
  mu = (float)mud;
  inv = (float)(1.0 / (sqrt(var) + (double)LN_EPS));
}

__global__ __launch_bounds__(256) void k_norm_elu_bf16(
    const u16* __restrict__ a, const float* __restrict__ g,
    const float* __restrict__ b, const float* __restrict__ ssum,
    const float* __restrict__ ssq, double cnt,
    u16* __restrict__ out, int n8, int Hmask) {
  float mu, inv;
  slot_stats(ssum, ssq, cnt, mu, inv);
  int id = blockIdx.x * blockDim.x + threadIdx.x;
  if (id >= n8) return;
  int i8 = id * 8;
  int cb = i8 & Hmask;
  uint4 v = *(const uint4*)(a + i8);
  const u32 va[4] = {v.x, v.y, v.z, v.w};
  uint4 o;
  u32* op = (u32*)&o;
#pragma unroll
  for (int w = 0; w < 4; w++) {
    float y0 = (bf2f(va[w] & 0xffffu) - mu) * inv * g[cb + 2 * w] + b[cb + 2 * w];
    float y1 = (bf2f(va[w] >> 16) - mu) * inv * g[cb + 2 * w + 1] + b[cb + 2 * w + 1];
    y0 = (y0 > 0.f) ? y0 : (__expf(y0) - 1.f);
    y1 = (y1 > 0.f) ? y1 : (__expf(y1) - 1.f);
    op[w] = (u32)f2bf(y0) | ((u32)f2bf(y1) << 16);
  }
  *(uint4*)(out + i8) = o;
}

__global__ __launch_bounds__(256) void k_norm_f32(
    float* __restrict__ a, const float* __restrict__ g,
    const float* __restrict__ b, const float* __restrict__ ssum,
    const float* __restrict__ ssq, double cnt, int n4, int Hmask) {
  float mu, inv;
  slot_stats(ssum, ssq, cnt, mu, inv);
  int id = blockIdx.x * blockDim.x + threadIdx.x;
  if (id >= n4) return;
  int i4 = id * 4;
  int cb = i4 & Hmask;
  float4 v = *(const float4*)(a + i4);
  float4 o;
  o.x = (v.x - mu) * inv * g[cb] + b[cb];
  o.y = (v.y - mu) * inv * g[cb + 1] + b[cb + 1];
  o.z = (v.z - mu) * inv * g[cb + 2] + b[cb + 2];
  o.w = (v.w - mu) * inv * g[cb + 3] + b[cb + 3];
  *(float4*)(a + i4) = o;
}

// ================= launch ====================================================
extern "C" void kernel_launch(void* const* d_in, const int* in_sizes, int n_in,
                              void* d_out, int out_size, void* d_ws, size_t ws_size,
                              hipStream_t stream) {
  const float* x   = (const float*)d_in[0];
  const float* Wq1 = (const float*)d_in[1];  const float* bq1 = (const float*)d_in[2];
  const float* Wk1 = (const float*)d_in[3];  const float* bk1 = (const float*)d_in[4];
  const float* Wv1 = (const float*)d_in[5];  const float* bv1 = (const float*)d_in[6];
  const float* Ws1 = (const float*)d_in[7];  const float* bs1 = (const float*)d_in[8];
  const float* g1  = (const float*)d_in[9];  const float* be1 = (const float*)d_in[10];
  const float* Wq2 = (const float*)d_in[11]; const float* bq2 = (const float*)d_in[12];
  const float* Wk2 = (const float*)d_in[13]; const float* bk2 = (const float*)d_in[14];
  const float* Wv2 = (const float*)d_in[15]; const float* bv2 = (const float*)d_in[16];
  const float* Ws2 = (const float*)d_in[17]; const float* bs2 = (const float*)d_in[18];
  const float* g2  = (const float*)d_in[19]; const float* be2 = (const float*)d_in[20];
  const int*   ei  = (const int*)d_in[21];

  const int N = in_sizes[0] / IN_DIM;   // 50000
  const int E = in_sizes[21] / 2;       // 800000
  const int* esrc = ei;
  const int* edst = ei + E;

  // ---- workspace carve (256B aligned); deg + slots adjacent -> 1 memset
  char* w = (char*)d_ws;
  auto carve = [&](size_t bytes) { char* p = w; w += (bytes + 255) & ~(size_t)255; return p; };
  int* deg     = (int*)carve((size_t)(N + 1) * 4);
  float* slots = (float*)carve(4 * NSLOT * 4);  // ssum1|ssq1|ssum2|ssq2
  u16* x_bf  = (u16*)carve((size_t)N * IN_DIM * 2);    // 51.2 MB; reused as h1
  u16* Wt1   = (u16*)carve((size_t)4 * HID * IN_DIM * 2);
  u16* Wt2   = (u16*)carve((size_t)4 * OUTD * HID * 2);
  float* bc1 = (float*)carve(4 * HID * 4);
  float* bc2 = (float*)carve(4 * OUTD * 4);
  u16* qs1   = (u16*)carve((size_t)N * 2 * HID * 2);   // Q1|S1 bf16 (51.2); reused qvs2 [N][3*OUTD]
  u16* kvt   = (u16*)carve((size_t)N * 2 * HID * 2);   // K1|V1 bf16 scratch; reused ktmp2 [N][OUTD]
  u8*  kv8   = (u8*)carve((size_t)N * 2 * HID);        // K1|V1 int8 (25.6); reused k82 [N][OUTD]
  float* sc1 = (float*)carve((size_t)N * 2 * 4);       // kscale,vscale; reused sc2 [N]
  u16* a1    = (u16*)carve((size_t)N * HID * 2);
  int* offs  = (int*)carve((size_t)(N + 1) * 4);
  int* cur   = (int*)carve((size_t)(N + 1) * 4);
  int* ssrc  = (int*)carve((size_t)E * 4);
  int* bsum  = (int*)carve(1024);
  int* boff  = (int*)carve(1024);
  u16* h1    = x_bf;
  u16* qvs2  = qs1;
  u16* ktmp2 = kvt;
  u8*  k82   = kv8;
  float* sc2 = sc1;
  float* ssum1 = slots, *ssq1 = slots + NSLOT;
  float* ssum2 = slots + 2 * NSLOT, *ssq2 = slots + 3 * NSLOT;

  hipMemsetAsync(deg, 0, (size_t)((char*)(slots + 4 * NSLOT) - (char*)deg), stream);

  // ---- K1: mega-prep ----
  int n4 = N * IN_DIM / 4;
  int b_cvt = (n4 + 255) / 256;
  int b_hist = (E + 255) / 256;
  int k1_blocks = b_cvt + b_hist + 6 + 512 + 128;
  k_prep<<<k1_blocks, 256, 0, stream>>>(
      x, x_bf, n4, edst, deg, E,
      bq1, bk1, bv1, bs1, bq2, bk2, bv2, bs2, bc1, bc2,
      Wq1, Wk1, Wv1, Ws1, Wq2, Wk2, Wv2, Ws2, Wt1, Wt2, b_cvt, b_hist);

  // ---- K2: parallel scan ----
  int nb = (N + 255) / 256;
  k_block_sum<<<nb, 256, 0, stream>>>(deg, bsum, N);
  k_scan_bsum<<<1, 256, 0, stream>>>(bsum, boff, nb);
  k_scan_final<<<nb, 256, 0, stream>>>(deg, boff, offs, cur, N, E);

  // ---- K3: gemm1 (Q->qs[0:256], K|V->kvt bf16, S->qs[256:512]) + scatter ----
  int mbx = (N + 127) / 128;                  // 391
  int g1_blocks = mbx * ((4 * HID) / 256);    // x4
  k_gemm<<<g1_blocks + b_hist, 256, 0, stream>>>(
      x_bf, Wt1, bc1, qs1, kvt, N, IN_DIM, 4 * HID, mbx,
      HID, 3 * HID, 2 * HID, 2 * HID, g1_blocks,
      esrc, edst, cur, ssrc, E);

  // ---- K4: quantize K1|V1 -> int8 + scales ----
  k_quant<HID, 2><<<(N * 2 + 3) / 4, 256, 0, stream>>>(kvt, kv8, sc1, N);

  // ---- K5: conv1 (K,V int8) + spread stats ----
  k_conv<HID, true, true><<<(N + 3) / 4, 256, 0, stream>>>(
      qs1, kv8, sc1, offs, ssrc, a1, nullptr, N, 1.0f / sqrtf((float)HID), ssum1, ssq1);

  // ---- K6: norm1 + ELU ----
  k_norm_elu_bf16<<<N * HID / 8 / 256, 256, 0, stream>>>(
      a1, g1, be1, ssum1, ssq1, (double)N * HID, h1, N * HID / 8, HID - 1);

  // ---- K7: gemm2 (Q->qvs[0:128], K->ktmp2, V->qvs[128:256], S->qvs[256:384]) ----
  int g2_blocks = mbx * ((4 * OUTD) / 256);   // x2
  k_gemm<<<g2_blocks, 256, 0, stream>>>(
      h1, Wt2, bc2, qvs2, ktmp2, N, HID, 4 * OUTD, mbx,
      OUTD, 2 * OUTD, 3 * OUTD, OUTD, g2_blocks,
      nullptr, nullptr, nullptr, nullptr, 0);

  // ---- K8: quantize K2 -> int8 + scale ----
  k_quant<OUTD, 1><<<(N + 3) / 4, 256, 0, stream>>>(ktmp2, k82, sc2, N);

  // ---- K9: conv2 (K int8, V bf16) + spread stats ----
  k_conv<OUTD, false, false><<<(N + 3) / 4, 256, 0, stream>>>(
      qvs2, k82, sc2, offs, ssrc, nullptr, (float*)d_out, N,
      1.0f / sqrtf((float)OUTD), ssum2, ssq2);

  // ---- K10: norm2 ----
  k_norm_f32<<<N * OUTD / 4 / 256, 256, 0, stream>>>(
      (float*)d_out, g2, be2, ssum2, ssq2, (double)N * OUTD, N * OUTD / 4, OUTD - 1);
}